// Round 1
// baseline (389.878 us; speedup 1.0000x reference)
//
#include <hip/hip_runtime.h>
#include <stdint.h>

// ---------------------------------------------------------------------------
// LinearBlockSparseAttention on MI355X (gfx950)
//   qkv = x @ Wqkv                      (bf16 MFMA GEMM, 16384x3072x1024)
//   per (b,h,m-block of 32 tokens):
//     qf = elu(q @ proj_h)+1, kf = elu(k @ proj_h)+1
//     S  = qf @ kf^T   (32x32)          [== qf @ (kf^T v) factored]
//     out = (S @ v) / (rowsum(S)+eps)
//   y = out @ Wout + bout               (bf16 MFMA GEMM, 16384x1024x1024)
// ---------------------------------------------------------------------------

typedef unsigned short u16;
typedef __attribute__((ext_vector_type(4))) float f32x4;
typedef __attribute__((ext_vector_type(8))) __bf16 bf16x8;
typedef __attribute__((ext_vector_type(8))) u16 us8;
typedef __attribute__((ext_vector_type(4))) u16 us4;

#define GLOAD_LDS16(g, l)                                                      \
  __builtin_amdgcn_global_load_lds(                                            \
      (const __attribute__((address_space(1))) void*)(g),                      \
      (__attribute__((address_space(3))) void*)(l), 16, 0, 0)

__device__ __forceinline__ u16 f2bf(float f) {
  union { float f; unsigned u; } x; x.f = f;
  return (u16)((x.u + 0x7fffu + ((x.u >> 16) & 1u)) >> 16);
}

__device__ __forceinline__ bf16x8 ld8(const void* p) {
  return __builtin_bit_cast(bf16x8, *(const us8*)p);
}

__device__ __forceinline__ f32x4 mfma16(bf16x8 a, bf16x8 b, f32x4 c) {
  return __builtin_amdgcn_mfma_f32_16x16x32_bf16(a, b, c, 0, 0, 0);
}

// ---------------------------------------------------------------------------
// elementwise fp32 -> bf16 cast (vectorized, grid-stride)
__global__ void cast_bf16_k(const float* __restrict__ in, u16* __restrict__ out,
                            int n4) {
  int stride = gridDim.x * blockDim.x;
  for (int i = blockIdx.x * blockDim.x + threadIdx.x; i < n4; i += stride) {
    f32x4 v = ((const f32x4*)in)[i];
    us4 o;
    o[0] = f2bf(v[0]); o[1] = f2bf(v[1]); o[2] = f2bf(v[2]); o[3] = f2bf(v[3]);
    ((us4*)out)[i] = o;
  }
}

// transpose + cast: in [R][C] f32 -> out [C][R] bf16
__global__ __launch_bounds__(256)
void tcast_k(const float* __restrict__ in, u16* __restrict__ out, int R, int C) {
  __shared__ float tile[32][33];
  int tx = threadIdx.x & 31, ty = threadIdx.x >> 5;  // 32 x 8
  int r0 = blockIdx.y * 32, c0 = blockIdx.x * 32;
#pragma unroll
  for (int i = 0; i < 32; i += 8)
    tile[ty + i][tx] = in[(size_t)(r0 + ty + i) * C + c0 + tx];
  __syncthreads();
#pragma unroll
  for (int i = 0; i < 32; i += 8)
    out[(size_t)(c0 + ty + i) * R + r0 + tx] = f2bf(tile[tx][ty + i]);
}

// proj [16][64][128] f32 -> projT [16][128][64] bf16
__global__ void pcast_k(const float* __restrict__ in, u16* __restrict__ out) {
  int idx = blockIdx.x * 256 + threadIdx.x;  // 16*128*64 = 131072 total
  int h = idx >> 13, f = (idx >> 6) & 127, e = idx & 63;
  out[idx] = f2bf(in[h * 8192 + e * 128 + f]);
}

// ---------------------------------------------------------------------------
// m97-structure GEMM: C[M,N] = A[M,K] @ Bt[N,K]^T  (bf16 in, fp32 acc)
// 128x128 tile, BK=32, 4 waves, 4x4 16x16x32 fragments per wave.
template <bool OUTF32>
__global__ __launch_bounds__(256)
void gemm_bt(const u16* __restrict__ A, const u16* __restrict__ Bt,
             const float* __restrict__ bias, void* __restrict__ Cv,
             int M, int N, int K) {
  __shared__ __align__(16) u16 As[128 * 32];
  __shared__ __align__(16) u16 Bs[128 * 32];
  const int tid = threadIdx.x, lane = tid & 63, wave = tid >> 6;
  const int wr = wave >> 1, wc = wave & 1;
  const int bxN = blockIdx.x * 128;  // col tile
  const int byM = blockIdx.y * 128;  // row tile
  const int lr = lane & 15, lg = lane >> 4;
  const int r_in = lane >> 2;          // 0..15 (staging row in 16-row chunk)
  const int kch = (lane & 3) * 8;      // 0,8,16,24 (staging k offset)

  f32x4 acc[4][4];
#pragma unroll
  for (int m = 0; m < 4; ++m)
#pragma unroll
    for (int n = 0; n < 4; ++n) acc[m][n] = (f32x4){0.f, 0.f, 0.f, 0.f};

  for (int kt = 0; kt < K; kt += 32) {
    __syncthreads();
#pragma unroll
    for (int c = 0; c < 2; ++c) {
      int rowA = byM + wave * 32 + c * 16 + r_in;
      int rowB = bxN + wave * 32 + c * 16 + r_in;
      GLOAD_LDS16(A + (size_t)rowA * K + kt + kch, As + (wave * 2 + c) * 512);
      GLOAD_LDS16(Bt + (size_t)rowB * K + kt + kch, Bs + (wave * 2 + c) * 512);
    }
    __syncthreads();
    bf16x8 a[4], b[4];
#pragma unroll
    for (int m = 0; m < 4; ++m)
      a[m] = ld8(&As[(wr * 64 + m * 16 + lr) * 32 + lg * 8]);
#pragma unroll
    for (int n = 0; n < 4; ++n)
      b[n] = ld8(&Bs[(wc * 64 + n * 16 + lr) * 32 + lg * 8]);
#pragma unroll
    for (int m = 0; m < 4; ++m)
#pragma unroll
      for (int n = 0; n < 4; ++n) acc[m][n] = mfma16(a[m], b[n], acc[m][n]);
  }

  const int rbase = byM + wr * 64 + lg * 4;
  const int cbase = bxN + wc * 64 + lr;
#pragma unroll
  for (int m = 0; m < 4; ++m) {
#pragma unroll
    for (int n = 0; n < 4; ++n) {
      int col = cbase + n * 16;
      float bia = OUTF32 ? bias[col] : 0.f;
#pragma unroll
      for (int r = 0; r < 4; ++r) {
        int row = rbase + m * 16 + r;
        if (OUTF32)
          ((float*)Cv)[(size_t)row * N + col] = acc[m][n][r] + bia;
        else
          ((u16*)Cv)[(size_t)row * N + col] = f2bf(acc[m][n][r]);
      }
    }
  }
}

// ---------------------------------------------------------------------------
// Fused block attention. 1 wave per (b, h, m-block).
// qkv row layout: [q(16h x 64) | k | v], token t = b*4096 + m*32 + s.
__global__ __launch_bounds__(64)
void attn_block_k(const u16* __restrict__ qkv, const u16* __restrict__ projT,
                  u16* __restrict__ attn) {
  __shared__ __align__(16) u16 qf_l[32 * 128];  // row stride 256 B, XOR-swizzled
  __shared__ __align__(16) u16 kf_l[32 * 128];
  __shared__ __align__(16) u16 V_l[32 * 72];    // padded rows (144 B)
  __shared__ __align__(16) u16 S_l[32 * 32];    // row stride 64 B, XOR-swizzled

  const int lane = threadIdx.x;
  const int bid = blockIdx.x;
  const int m = bid & 127, h = (bid >> 7) & 15, b = bid >> 11;
  const size_t t0 = (size_t)b * 4096 + (size_t)m * 32;
  const u16* qb = qkv + t0 * 3072 + h * 64;
  const u16* kb = qb + 1024;
  const u16* vb = qb + 2048;
  const u16* pT = projT + h * 8192;  // [128][64]
  const int lr = lane & 15, lg = lane >> 4;

  // proj B-fragments: bp[f][ks] holds P[e = ks*32+lg*8+j][fcol = f*16+lr]
  bf16x8 bp[8][2];
#pragma unroll
  for (int f = 0; f < 8; ++f)
#pragma unroll
    for (int ks = 0; ks < 2; ++ks)
      bp[f][ks] = ld8(&pT[(f * 16 + lr) * 64 + ks * 32 + lg * 8]);

  // stage V rows (coalesced 16B per lane)
#pragma unroll
  for (int it = 0; it < 4; ++it) {
    int s = it * 8 + (lane >> 3);
    int d0 = (lane & 7) * 8;
    *(us8*)&V_l[s * 72 + d0] = *(const us8*)&vb[(size_t)s * 3072 + d0];
  }

  // qf / kf: feature map, elu(x)+1, into swizzled LDS
#pragma unroll
  for (int pass = 0; pass < 2; ++pass) {
    const u16* src = pass ? kb : qb;
    u16* dst = pass ? kf_l : qf_l;
    f32x4 acc[2][8];
#pragma unroll
    for (int mm = 0; mm < 2; ++mm)
#pragma unroll
      for (int f = 0; f < 8; ++f) acc[mm][f] = (f32x4){0.f, 0.f, 0.f, 0.f};
    bf16x8 afr[2][2];
#pragma unroll
    for (int mm = 0; mm < 2; ++mm)
#pragma unroll
      for (int ks = 0; ks < 2; ++ks)
        afr[mm][ks] = ld8(&src[(size_t)(mm * 16 + lr) * 3072 + ks * 32 + lg * 8]);
#pragma unroll
    for (int mm = 0; mm < 2; ++mm)
#pragma unroll
      for (int ks = 0; ks < 2; ++ks)
#pragma unroll
        for (int f = 0; f < 8; ++f)
          acc[mm][f] = mfma16(afr[mm][ks], bp[f][ks], acc[mm][f]);
#pragma unroll
    for (int mm = 0; mm < 2; ++mm)
#pragma unroll
      for (int f = 0; f < 8; ++f)
#pragma unroll
        for (int r = 0; r < 4; ++r) {
          float x = acc[mm][f][r];
          float v = x > 0.f ? x + 1.f : __expf(x);  // elu(x)+1
          int row = mm * 16 + lg * 4 + r;
          int byi = (f * 16 + lr) * 2;
          *(u16*)((char*)dst + row * 256 + (byi ^ ((row & 7) << 4))) = f2bf(v);
        }
  }

  // S = qf @ kf^T  (32x32, K=128)
  f32x4 sacc[2][2];
#pragma unroll
  for (int mm = 0; mm < 2; ++mm)
#pragma unroll
    for (int nn = 0; nn < 2; ++nn) sacc[mm][nn] = (f32x4){0.f, 0.f, 0.f, 0.f};
#pragma unroll
  for (int ks = 0; ks < 4; ++ks) {
    int byi = (ks * 32 + lg * 8) * 2;
    bf16x8 aq[2], bk[2];
#pragma unroll
    for (int mm = 0; mm < 2; ++mm) {
      int row = mm * 16 + lr;
      aq[mm] = ld8((char*)qf_l + row * 256 + (byi ^ ((row & 7) << 4)));
      bk[mm] = ld8((char*)kf_l + row * 256 + (byi ^ ((row & 7) << 4)));
    }
#pragma unroll
    for (int mm = 0; mm < 2; ++mm)
#pragma unroll
      for (int nn = 0; nn < 2; ++nn)
        sacc[mm][nn] = mfma16(aq[mm], bk[nn], sacc[mm][nn]);
  }

  // row sums (z denominator): reduce over the 16-lane column group
  float rs[2][4];
#pragma unroll
  for (int mm = 0; mm < 2; ++mm)
#pragma unroll
    for (int r = 0; r < 4; ++r) {
      float t = sacc[mm][0][r] + sacc[mm][1][r];
      t += __shfl_xor(t, 1);
      t += __shfl_xor(t, 2);
      t += __shfl_xor(t, 4);
      t += __shfl_xor(t, 8);
      rs[mm][r] = t;
    }

  // S -> bf16 LDS (swizzled, 64 B rows)
#pragma unroll
  for (int mm = 0; mm < 2; ++mm)
#pragma unroll
    for (int nn = 0; nn < 2; ++nn)
#pragma unroll
      for (int r = 0; r < 4; ++r) {
        int row = mm * 16 + lg * 4 + r;
        int byi = (nn * 16 + lr) * 2;
        *(u16*)((char*)S_l + row * 64 + (byi ^ ((row & 3) << 4))) =
            f2bf(sacc[mm][nn][r]);
      }

  // PV: out = S @ V  (32x64, K=32), V B-frags gathered from padded LDS
  bf16x8 vfr[4];
#pragma unroll
  for (int nn = 0; nn < 4; ++nn) {
    us8 g;
#pragma unroll
    for (int j = 0; j < 8; ++j) g[j] = V_l[(lg * 8 + j) * 72 + nn * 16 + lr];
    vfr[nn] = __builtin_bit_cast(bf16x8, g);
  }
  f32x4 pacc[2][4];
#pragma unroll
  for (int mm = 0; mm < 2; ++mm)
#pragma unroll
    for (int nn = 0; nn < 4; ++nn) pacc[mm][nn] = (f32x4){0.f, 0.f, 0.f, 0.f};
#pragma unroll
  for (int mm = 0; mm < 2; ++mm) {
    int row = mm * 16 + lr;
    int byi = lg * 16;
    bf16x8 a = ld8((char*)S_l + row * 64 + (byi ^ ((row & 3) << 4)));
#pragma unroll
    for (int nn = 0; nn < 4; ++nn) pacc[mm][nn] = mfma16(a, vfr[nn], pacc[mm][nn]);
  }

  // normalize + write bf16 attn output [16384][1024]
#pragma unroll
  for (int mm = 0; mm < 2; ++mm)
#pragma unroll
    for (int r = 0; r < 4; ++r) {
      float z = 1.f / (rs[mm][r] + 1e-8f);
      int q = mm * 16 + lg * 4 + r;
#pragma unroll
      for (int nn = 0; nn < 4; ++nn)
        attn[(t0 + q) * 1024 + h * 64 + nn * 16 + lr] =
            f2bf(pacc[mm][nn][r] * z);
    }
}

// ---------------------------------------------------------------------------
extern "C" void kernel_launch(void* const* d_in, const int* in_sizes, int n_in,
                              void* d_out, int out_size, void* d_ws,
                              size_t ws_size, hipStream_t stream) {
  const float* x = (const float*)d_in[0];     // [4,4096,1024]
  const float* Wqkv = (const float*)d_in[1];  // [1024,3072]
  const float* proj = (const float*)d_in[2];  // [16,64,128]
  const float* Wout = (const float*)d_in[3];  // [1024,1024]
  const float* bout = (const float*)d_in[4];  // [1024]
  float* out = (float*)d_out;                 // [4,4096,1024] fp32

  // workspace layout (bytes)
  char* ws = (char*)d_ws;
  u16* xb    = (u16*)(ws + 0);          // 16384*1024*2   = 33,554,432
  u16* wqkvT = (u16*)(ws + 33554432);   // 3072*1024*2    =  6,291,456
  u16* qkv   = (u16*)(ws + 39845888);   // 16384*3072*2   = 100,663,296
  u16* projT = (u16*)(ws + 140509184);  // 16*128*64*2    =    262,144
  u16* attn  = (u16*)(ws + 140771328);  // 16384*1024*2   = 33,554,432
  u16* woutT = (u16*)(ws + 174325760);  // 1024*1024*2    =  2,097,152

  cast_bf16_k<<<2048, 256, 0, stream>>>(x, xb, (16384 * 1024) / 4);
  tcast_k<<<dim3(3072 / 32, 1024 / 32), 256, 0, stream>>>(Wqkv, wqkvT, 1024, 3072);
  tcast_k<<<dim3(1024 / 32, 1024 / 32), 256, 0, stream>>>(Wout, woutT, 1024, 1024);
  pcast_k<<<512, 256, 0, stream>>>(proj, projT);

  gemm_bt<false><<<dim3(3072 / 128, 16384 / 128), 256, 0, stream>>>(
      xb, wqkvT, nullptr, qkv, 16384, 3072, 1024);

  attn_block_k<<<8192, 64, 0, stream>>>(qkv, projT, attn);

  gemm_bt<true><<<dim3(1024 / 128, 16384 / 128), 256, 0, stream>>>(
      attn, woutT, bout, out, 16384, 1024, 1024);
}